// Round 3
// baseline (449.049 us; speedup 1.0000x reference)
//
#include <hip/hip_runtime.h>
#include <hip/hip_bf16.h>

// Problem: B=8,N=256,C=512,H=W=8 -> x[8,256,512,64].
// Dtype model (R1: NaN reading inputs as bf16 => inputs fp32. R2: absmax 1.86e-2
// matches EXACTLY the signature of u16-bf16 writes into an fp32 output buffer
// (flat[i]~=ref[2i+1], second half 0 => predicted 1.91e-2). The "bf16" in the
// test label is hardcoded in both f-string branches — carries no dtype info.)
//   => ALL inputs fp32, OUTPUT fp32.
//
// Algebra: att_i is scalar per (b,n); mean is linear => 3-iter attention loop
// collapses to: m0 = mean(x); s1=sig(conv(m0)); s2=sig(conv(m0*s1)); s3=sig(conv(m0*s1*s2));
// scale = s1*s2*s3; out = ((scale * (x . Ws)) + bs) @ fc_w^T + fc_b.
// => 268 MB x read exactly ONCE (K1 computes m0 and unscaled y' together).

typedef unsigned short u16;
typedef __attribute__((ext_vector_type(8))) short short8;     // 8 bf16 = 4 VGPRs (MFMA A/B frag)
typedef __attribute__((ext_vector_type(4))) float floatx4;

#define Bb 8
#define Nn 256
#define Cc 512
#define HWs 64
#define BN 2048          // B*N rows
#define DIMd 1024

__device__ inline u16 f2bf(float f) {
    unsigned int u = __builtin_bit_cast(unsigned int, f);
    unsigned int r = (u + 0x7FFFu + ((u >> 16) & 1u)) >> 16;   // RNE
    return (u16)r;
}

// ---------------- K1: fused mean-reduction + grouped Linear(HW,2) -----------------
// grid = 2048 blocks (one per (b,n)), 256 threads.
// Thread t, pass p: channel c = p*64 + (t>>2), quarter q = t&3 handles x[c, q*16..q*16+16).
// Global x offset = p*4096 + t*16 floats -> 64 B/lane contiguous, fully coalesced.
__global__ __launch_bounds__(256) void k1_reduce_grouped(
    const float* __restrict__ x, const float* __restrict__ Ws,
    float* __restrict__ yprime, float* __restrict__ m0)
{
    const int bid = blockIdx.x;
    const int tid = threadIdx.x;
    const float* xb = x + (size_t)bid * (Cc * HWs);
    const int q = tid & 3;
    const int cofs = tid >> 2;
    float lsum = 0.f;

    for (int p = 0; p < 8; ++p) {
        const int c = p * 64 + cofs;
        const floatx4* xp  = (const floatx4*)(xb + p * 4096 + tid * 16);
        const floatx4* w0p = (const floatx4*)(Ws + (size_t)(c * 2 + 0) * HWs + q * 16);
        const floatx4* w1p = (const floatx4*)(Ws + (size_t)(c * 2 + 1) * HWs + q * 16);
        float d0 = 0.f, d1 = 0.f;
        #pragma unroll
        for (int v = 0; v < 4; ++v) {
            floatx4 xv = xp[v];
            floatx4 w0 = w0p[v];
            floatx4 w1 = w1p[v];
            #pragma unroll
            for (int j = 0; j < 4; ++j) {
                d0 += xv[j] * w0[j];
                d1 += xv[j] * w1[j];
                lsum += xv[j];
            }
        }
        // reduce dots over the 4-lane group sharing channel c
        d0 += __shfl_xor(d0, 1); d0 += __shfl_xor(d0, 2);
        d1 += __shfl_xor(d1, 1); d1 += __shfl_xor(d1, 2);
        if (q == 0) {
            yprime[(size_t)bid * DIMd + c * 2 + 0] = d0;
            yprime[(size_t)bid * DIMd + c * 2 + 1] = d1;
        }
    }
    // block-wide sum for the mean over all 32768 elements of this (b,n)
    #pragma unroll
    for (int s = 32; s; s >>= 1) lsum += __shfl_xor(lsum, s);
    __shared__ float wsum[4];
    if ((tid & 63) == 0) wsum[tid >> 6] = lsum;
    __syncthreads();
    if (tid == 0)
        m0[bid] = (wsum[0] + wsum[1] + wsum[2] + wsum[3]) * (1.0f / 32768.f);
}

// ---------------- K2: 3x (conv1d k=5 same + sigmoid) scale recurrence -----------------
// grid = 8 blocks (one per b), 256 threads (one per n).
__global__ __launch_bounds__(256) void k2_scale(
    const float* __restrict__ m0, const float* __restrict__ conv_w,
    const float* __restrict__ conv_b, float* __restrict__ scale)
{
    const int b = blockIdx.x;
    const int n = threadIdx.x;
    __shared__ float buf[Nn];
    float a = m0[b * Nn + n];
    float p = 1.f;
    for (int i = 0; i < 3; ++i) {
        buf[n] = a;
        __syncthreads();
        float t = 0.f;
        #pragma unroll
        for (int k = 0; k < 5; ++k) {
            int idx = n + k - 2;
            float v = (idx >= 0 && idx < Nn) ? buf[idx] : 0.f;
            t += v * conv_w[i * 5 + k];
        }
        t += conv_b[i];
        float s = 1.f / (1.f + __expf(-t));
        p *= s;
        a *= s;
        __syncthreads();
    }
    scale[b * Nn + n] = p;
}

// ---------------- K3: out[2048,1024] = (scale*y' + bs) @ fc_w^T + fc_b (bf16 MFMA) ------
// grid (32,16) -> 64x64 C-tile per block; 4 waves, each 32x32 via 2x2 of 16x16x32 MFMA.
// A frag: A[m=lane&15][k=quad*8+j]; B frag: B[k=quad*8+j][n=lane&15] (fc_w row-major [n][k]).
// C/D: col=lane&15, row=quad*4+reg.  Output stored as fp32.
__global__ __launch_bounds__(256) void k3_gemm(
    const float* __restrict__ yprime, const float* __restrict__ scale,
    const float* __restrict__ bs, const float* __restrict__ fc_w,
    const float* __restrict__ fc_b, float* __restrict__ out)
{
    const int tid = threadIdx.x;
    const int w = tid >> 6;
    const int lane = tid & 63;
    const int l15 = lane & 15;
    const int quad = lane >> 4;
    const int wm = w & 1, wn = w >> 1;
    const int r0 = blockIdx.x * 64 + wm * 32;
    const int c0 = blockIdx.y * 64 + wn * 32;

    floatx4 acc[2][2] = {};
    const int rowA0 = r0 + l15;
    const float sc0 = scale[rowA0];
    const float sc1 = scale[rowA0 + 16];

    for (int k0 = 0; k0 < DIMd; k0 += 32) {
        const int ka = k0 + quad * 8;
        const floatx4* bsp = (const floatx4*)(bs + ka);
        floatx4 bs0 = bsp[0], bs1 = bsp[1];
        short8 afr[2], bfr[2];
        #pragma unroll
        for (int mi = 0; mi < 2; ++mi) {
            const int row = rowA0 + mi * 16;
            const floatx4* yp = (const floatx4*)(yprime + (size_t)row * DIMd + ka);
            floatx4 y0 = yp[0], y1 = yp[1];
            const float sc = mi ? sc1 : sc0;
            short8 af;
            #pragma unroll
            for (int j = 0; j < 4; ++j) af[j]     = (short)f2bf(sc * y0[j] + bs0[j]);
            #pragma unroll
            for (int j = 0; j < 4; ++j) af[4 + j] = (short)f2bf(sc * y1[j] + bs1[j]);
            afr[mi] = af;
        }
        #pragma unroll
        for (int ni = 0; ni < 2; ++ni) {
            const int col = c0 + ni * 16 + l15;
            const floatx4* bp = (const floatx4*)(fc_w + (size_t)col * DIMd + ka);
            floatx4 b0 = bp[0], b1 = bp[1];
            short8 bf;
            #pragma unroll
            for (int j = 0; j < 4; ++j) { bf[j] = (short)f2bf(b0[j]); bf[4 + j] = (short)f2bf(b1[j]); }
            bfr[ni] = bf;
        }
        #pragma unroll
        for (int mi = 0; mi < 2; ++mi)
            #pragma unroll
            for (int ni = 0; ni < 2; ++ni)
                acc[mi][ni] = __builtin_amdgcn_mfma_f32_16x16x32_bf16(afr[mi], bfr[ni], acc[mi][ni], 0, 0, 0);
    }

    #pragma unroll
    for (int ni = 0; ni < 2; ++ni) {
        const int col = c0 + ni * 16 + l15;
        const float fb = fc_b[col];
        #pragma unroll
        for (int mi = 0; mi < 2; ++mi) {
            #pragma unroll
            for (int r = 0; r < 4; ++r) {
                const int row = r0 + mi * 16 + quad * 4 + r;
                out[(size_t)row * DIMd + col] = acc[mi][ni][r] + fb;
            }
        }
    }
}

extern "C" void kernel_launch(void* const* d_in, const int* in_sizes, int n_in,
                              void* d_out, int out_size, void* d_ws, size_t ws_size,
                              hipStream_t stream) {
    const float* x      = (const float*)d_in[0];   // [8,256,512,8,8] f32
    const float* conv_w = (const float*)d_in[1];   // [3,5] f32
    const float* conv_b = (const float*)d_in[2];   // [3] f32
    const float* Ws     = (const float*)d_in[3];   // [512,2,64] f32
    const float* bs     = (const float*)d_in[4];   // [512,2] f32
    const float* fc_w   = (const float*)d_in[5];   // [1024,1024] f32
    const float* fc_b   = (const float*)d_in[6];   // [1024] f32
    float* out = (float*)d_out;                    // [8,256,1024] f32

    // workspace layout (8.02 MB used): m0[2048] f32 | scale[2048] f32 | yprime[2048*1024] f32
    float* m0     = (float*)d_ws;
    float* scale  = m0 + BN;
    float* yprime = scale + BN;

    k1_reduce_grouped<<<dim3(BN), dim3(256), 0, stream>>>(x, Ws, yprime, m0);
    k2_scale<<<dim3(Bb), dim3(Nn), 0, stream>>>(m0, conv_w, conv_b, scale);
    k3_gemm<<<dim3(32, 16), dim3(256), 0, stream>>>(yprime, scale, bs, fc_w, fc_b, out);
}

// Round 4
// 423.418 us; speedup vs baseline: 1.0605x; 1.0605x over previous
//
#include <hip/hip_runtime.h>
#include <hip/hip_bf16.h>

// Problem: B=8,N=256,C=512,H=W=8 -> x[8,256,512,64]. All inputs fp32, output fp32
// (verified R3: passed, absmax 6.1e-5).
//
// Algebra: att_i is scalar per (b,n); mean is linear => 3-iter attention loop
// collapses to m0 = mean(x); scale = s1*s2*s3 (tiny recurrence). Grouped linear
// is linear in x, and scale is per-row, so:
//   out = scale o (y' @ fc_w^T) + (bs @ fc_w^T + fc_b),   y' = x . Ws (unscaled)
// => x (268 MB) read exactly once (K1); all bf16 conversions hoisted out of the
// GEMM K-loop (K0a pre-converts fc_w, K1 writes y' as bf16, K0b folds bias).

typedef unsigned short u16;
typedef unsigned int u32;
typedef __attribute__((ext_vector_type(8))) short short8;     // 8 bf16 = 4 VGPRs (MFMA A/B frag)
typedef __attribute__((ext_vector_type(4))) float floatx4;

#define Bb 8
#define Nn 256
#define Cc 512
#define HWs 64
#define BN 2048          // B*N rows
#define DIMd 1024

__device__ inline u16 f2bf(float f) {
    unsigned int u = __builtin_bit_cast(unsigned int, f);
    unsigned int r = (u + 0x7FFFu + ((u >> 16) & 1u)) >> 16;   // RNE
    return (u16)r;
}

// ---------------- K0a: fc_w fp32 -> bf16 (1M elements) -----------------
// grid 1024 x 256; one float4 per thread.
__global__ __launch_bounds__(256) void k0a_cvt_w(
    const float* __restrict__ w, u16* __restrict__ wb)
{
    const int i = blockIdx.x * 256 + threadIdx.x;      // float4 index, 262144 total
    floatx4 v = ((const floatx4*)w)[i];
    u32 lo = (u32)f2bf(v[0]) | ((u32)f2bf(v[1]) << 16);
    u32 hi = (u32)f2bf(v[2]) | ((u32)f2bf(v[3]) << 16);
    ((u32*)wb)[i * 2 + 0] = lo;
    ((u32*)wb)[i * 2 + 1] = hi;
}

// ---------------- K0b: bias2[c] = dot(bs_vec, fc_w[c,:]) + fc_b[c] (fp32) ------
// grid 256 blocks x 256 threads; one wave per output col (1024 cols).
__global__ __launch_bounds__(256) void k0b_bias(
    const float* __restrict__ bs, const float* __restrict__ fc_w,
    const float* __restrict__ fc_b, float* __restrict__ bias2)
{
    const int wv = blockIdx.x * 4 + (threadIdx.x >> 6);  // 0..1023 = output col
    const int lane = threadIdx.x & 63;
    const floatx4* bp = (const floatx4*)(fc_w + (size_t)wv * DIMd + lane * 16);
    const floatx4* sp = (const floatx4*)(bs + lane * 16);
    float s = 0.f;
    #pragma unroll
    for (int v = 0; v < 4; ++v) {
        floatx4 a = bp[v], b = sp[v];
        #pragma unroll
        for (int j = 0; j < 4; ++j) s += a[j] * b[j];
    }
    #pragma unroll
    for (int sft = 32; sft; sft >>= 1) s += __shfl_xor(s, sft);
    if (lane == 0) bias2[wv] = s + fc_b[wv];
}

// ---------------- K1: fused mean-reduction + grouped Linear(HW,2), bf16 y' out ----
// grid = 2048 blocks (one per (b,n)), 256 threads.
// Thread t, pass p: channel c = p*64 + (t>>2), quarter q = t&3 handles x[c, q*16..+16).
// x offset = p*4096 + t*16 floats -> 64 B/lane contiguous, fully coalesced.
__global__ __launch_bounds__(256) void k1_reduce_grouped(
    const float* __restrict__ x, const float* __restrict__ Ws,
    u16* __restrict__ ybf, float* __restrict__ m0)
{
    const int bid = blockIdx.x;
    const int tid = threadIdx.x;
    const float* xb = x + (size_t)bid * (Cc * HWs);
    const int q = tid & 3;
    const int cofs = tid >> 2;
    float lsum = 0.f;

    for (int p = 0; p < 8; ++p) {
        const int c = p * 64 + cofs;
        const floatx4* xp  = (const floatx4*)(xb + p * 4096 + tid * 16);
        const floatx4* w0p = (const floatx4*)(Ws + (size_t)(c * 2 + 0) * HWs + q * 16);
        const floatx4* w1p = (const floatx4*)(Ws + (size_t)(c * 2 + 1) * HWs + q * 16);
        float d0 = 0.f, d1 = 0.f;
        #pragma unroll
        for (int v = 0; v < 4; ++v) {
            floatx4 xv = xp[v];
            floatx4 w0 = w0p[v];
            floatx4 w1 = w1p[v];
            #pragma unroll
            for (int j = 0; j < 4; ++j) {
                d0 += xv[j] * w0[j];
                d1 += xv[j] * w1[j];
                lsum += xv[j];
            }
        }
        // reduce dots over the 4-lane group sharing channel c
        d0 += __shfl_xor(d0, 1); d0 += __shfl_xor(d0, 2);
        d1 += __shfl_xor(d1, 1); d1 += __shfl_xor(d1, 2);
        if (q == 0) {
            // pack (d0,d1) -> 2 bf16 in one dword; word index = bid*512 + c
            u32 pk = (u32)f2bf(d0) | ((u32)f2bf(d1) << 16);
            ((u32*)ybf)[(size_t)bid * (DIMd / 2) + c] = pk;
        }
    }
    // block-wide sum for the mean over all 32768 elements of this (b,n)
    #pragma unroll
    for (int s = 32; s; s >>= 1) lsum += __shfl_xor(lsum, s);
    __shared__ float wsum[4];
    if ((tid & 63) == 0) wsum[tid >> 6] = lsum;
    __syncthreads();
    if (tid == 0)
        m0[bid] = (wsum[0] + wsum[1] + wsum[2] + wsum[3]) * (1.0f / 32768.f);
}

// ---------------- K2: 3x (conv1d k=5 same + sigmoid) scale recurrence -----------------
// grid = 8 blocks (one per b), 256 threads (one per n).
__global__ __launch_bounds__(256) void k2_scale(
    const float* __restrict__ m0, const float* __restrict__ conv_w,
    const float* __restrict__ conv_b, float* __restrict__ scale)
{
    const int b = blockIdx.x;
    const int n = threadIdx.x;
    __shared__ float buf[Nn];
    float a = m0[b * Nn + n];
    float p = 1.f;
    for (int i = 0; i < 3; ++i) {
        buf[n] = a;
        __syncthreads();
        float t = 0.f;
        #pragma unroll
        for (int k = 0; k < 5; ++k) {
            int idx = n + k - 2;
            float v = (idx >= 0 && idx < Nn) ? buf[idx] : 0.f;
            t += v * conv_w[i * 5 + k];
        }
        t += conv_b[i];
        float s = 1.f / (1.f + __expf(-t));
        p *= s;
        a *= s;
        __syncthreads();
    }
    scale[b * Nn + n] = p;
}

// ---------------- K3: out = scale o (Ybf @ Wbf^T) + bias2  (pure bf16 MFMA) ------
// grid (32,16) -> 64x64 C-tile per block; 4 waves, each 32x32 via 2x2 of 16x16x32 MFMA.
// A frag: A[m=lane&15][k=quad*8+j] from ybf; B frag: B[n=lane&15][k] from wbf
// (row-major [n][k]). C/D: col=lane&15, row=quad*4+reg. Zero per-iter conversion VALU.
__global__ __launch_bounds__(256) void k3_gemm(
    const u16* __restrict__ ybf, const u16* __restrict__ wbf,
    const float* __restrict__ scale, const float* __restrict__ bias2,
    float* __restrict__ out)
{
    const int tid = threadIdx.x;
    const int w = tid >> 6;
    const int lane = tid & 63;
    const int l15 = lane & 15;
    const int quad = lane >> 4;
    const int wm = w & 1, wn = w >> 1;
    const int r0 = blockIdx.x * 64 + wm * 32;
    const int c0 = blockIdx.y * 64 + wn * 32;

    floatx4 acc[2][2] = {};
    const u16* aptr0 = ybf + (size_t)(r0 + l15) * DIMd + quad * 8;
    const u16* aptr1 = aptr0 + 16 * DIMd;
    const u16* bptr0 = wbf + (size_t)(c0 + l15) * DIMd + quad * 8;
    const u16* bptr1 = bptr0 + 16 * DIMd;

    for (int k0 = 0; k0 < DIMd; k0 += 32) {
        short8 a0 = *(const short8*)(aptr0 + k0);
        short8 a1 = *(const short8*)(aptr1 + k0);
        short8 b0 = *(const short8*)(bptr0 + k0);
        short8 b1 = *(const short8*)(bptr1 + k0);
        acc[0][0] = __builtin_amdgcn_mfma_f32_16x16x32_bf16(a0, b0, acc[0][0], 0, 0, 0);
        acc[0][1] = __builtin_amdgcn_mfma_f32_16x16x32_bf16(a0, b1, acc[0][1], 0, 0, 0);
        acc[1][0] = __builtin_amdgcn_mfma_f32_16x16x32_bf16(a1, b0, acc[1][0], 0, 0, 0);
        acc[1][1] = __builtin_amdgcn_mfma_f32_16x16x32_bf16(a1, b1, acc[1][1], 0, 0, 0);
    }

    #pragma unroll
    for (int ni = 0; ni < 2; ++ni) {
        const int col = c0 + ni * 16 + l15;
        const float b2 = bias2[col];
        #pragma unroll
        for (int mi = 0; mi < 2; ++mi) {
            #pragma unroll
            for (int r = 0; r < 4; ++r) {
                const int row = r0 + mi * 16 + quad * 4 + r;
                out[(size_t)row * DIMd + col] = scale[row] * acc[mi][ni][r] + b2;
            }
        }
    }
}

extern "C" void kernel_launch(void* const* d_in, const int* in_sizes, int n_in,
                              void* d_out, int out_size, void* d_ws, size_t ws_size,
                              hipStream_t stream) {
    const float* x      = (const float*)d_in[0];   // [8,256,512,8,8] f32
    const float* conv_w = (const float*)d_in[1];   // [3,5] f32
    const float* conv_b = (const float*)d_in[2];   // [3] f32
    const float* Ws     = (const float*)d_in[3];   // [512,2,64] f32
    const float* bs     = (const float*)d_in[4];   // [512,2] f32
    const float* fc_w   = (const float*)d_in[5];   // [1024,1024] f32
    const float* fc_b   = (const float*)d_in[6];   // [1024] f32
    float* out = (float*)d_out;                    // [8,256,1024] f32

    // workspace: m0[2048] f32 | scale[2048] f32 | bias2[1024] f32 |
    //            ybf[2048*1024] bf16 (4MB) | wbf[1024*1024] bf16 (2MB)
    float* m0    = (float*)d_ws;
    float* scale = m0 + BN;
    float* bias2 = scale + BN;
    u16*   ybf   = (u16*)(bias2 + DIMd);
    u16*   wbf   = ybf + (size_t)BN * DIMd;

    k0a_cvt_w<<<dim3(1024), dim3(256), 0, stream>>>(fc_w, wbf);
    k0b_bias<<<dim3(256), dim3(256), 0, stream>>>(bs, fc_w, fc_b, bias2);
    k1_reduce_grouped<<<dim3(BN), dim3(256), 0, stream>>>(x, Ws, ybf, m0);
    k2_scale<<<dim3(Bb), dim3(Nn), 0, stream>>>(m0, conv_w, conv_b, scale);
    k3_gemm<<<dim3(32, 16), dim3(256), 0, stream>>>(ybf, wbf, scale, bias2, out);
}